// Round 11
// baseline (2341.955 us; speedup 1.0000x reference)
//
#include <hip/hip_runtime.h>

typedef __attribute__((ext_vector_type(8))) short bf16x8;
typedef __attribute__((ext_vector_type(4))) float f32x4;

#define BDIM 32768
#define DDIM 2048
#define HNUM 16
#define HD   128

// ---------- helpers ----------
__device__ inline short f2bf(float f) {
    union { float f; unsigned u; } v; v.f = f;
    unsigned r = v.u + 0x7FFFu + ((v.u >> 16) & 1u);   // round-to-nearest-even
    return (short)(r >> 16);
}
__device__ inline float bf2f(short s) {
    union { unsigned u; float f; } v; v.u = ((unsigned)(unsigned short)s) << 16; return v.f;
}
__device__ inline unsigned pk2(float lo, float hi) {
    return (unsigned)(unsigned short)f2bf(lo) | (((unsigned)(unsigned short)f2bf(hi)) << 16);
}
__device__ inline bf16x8 pack8(float4 a, float4 b) {
    union { bf16x8 v; unsigned u[4]; } t;
    t.u[0] = pk2(a.x, a.y); t.u[1] = pk2(a.z, a.w);
    t.u[2] = pk2(b.x, b.y); t.u[3] = pk2(b.z, b.w);
    return t.v;
}

__device__ inline void load_lds16(const void* g, void* l) {
    __builtin_amdgcn_global_load_lds(
        (const __attribute__((address_space(1))) void*)g,
        (__attribute__((address_space(3))) void*)l, 16, 0, 0);
}

#define VMCNT(n) asm volatile("s_waitcnt vmcnt(" #n ")" ::: "memory")
#define LGKMF    asm volatile("s_waitcnt lgkmcnt(0)" ::: "memory")
#define BARX     do { __builtin_amdgcn_s_barrier(); __builtin_amdgcn_sched_barrier(0); } while (0)
#define SP1      __builtin_amdgcn_s_setprio(1)
#define SP0      __builtin_amdgcn_s_setprio(0)

// ---------- weight transpose + convert: W[K][N] fp32 -> Wt[N][K] bf16 ----------
__global__ __launch_bounds__(256)
void wtrans(const float* __restrict__ w0, const float* __restrict__ w1,
            const float* __restrict__ w2, const float* __restrict__ w3,
            short* __restrict__ o0, short* __restrict__ o1,
            short* __restrict__ o2, short* __restrict__ o3)
{
    const float* W = blockIdx.z == 0 ? w0 : blockIdx.z == 1 ? w1 : blockIdx.z == 2 ? w2 : w3;
    short*       O = blockIdx.z == 0 ? o0 : blockIdx.z == 1 ? o1 : blockIdx.z == 2 ? o2 : o3;
    __shared__ float t[32][33];
    int bx = blockIdx.x * 32;   // n
    int by = blockIdx.y * 32;   // k
    int tx = threadIdx.x, ty = threadIdx.y;  // 32 x 8
    #pragma unroll
    for (int r = 0; r < 4; ++r)
        t[ty + 8*r][tx] = W[(size_t)(by + ty + 8*r) * DDIM + bx + tx];
    __syncthreads();
    #pragma unroll
    for (int r = 0; r < 4; ++r)
        O[(size_t)(bx + ty + 8*r) * DDIM + by + tx] = f2bf(t[tx][ty + 8*r]);
}

// ---------- 256x256 8-wave 8-phase bf16 GEMM (r6 skeleton) ----------
// AMODE 0: A bf16 via global_load_lds (exact r6 schedule, best measured 291us).
// AMODE 1: A fp32 -> reg-stage (global_load_dwordx4 -> RNE cvt -> ds_write_b128,
//   swizzle applied on the write side). vmcnt(6) moves to ph3/ph7 (lands the A
//   regs + the consumed tile's B gloads); lgkmcnt(0) after write-phases
//   publishes ds_writes before the next barrier. Ledger: steady queue 8..18,
//   waits land exactly 12 oldest; prologue vmcnt(8); epilogue vmcnt(0).
// MODE 0: bf16 out. MODE 1: f32 out + bf16 resid.

template<int MH, int NH>
__device__ inline void quadf(f32x4 (&acc)[8][4], bf16x8 (&a)[4][2], bf16x8 (&b)[2][2])
{
    #pragma unroll
    for (int kk = 0; kk < 2; ++kk)
        #pragma unroll
        for (int mi = 0; mi < 4; ++mi)
            #pragma unroll
            for (int ni = 0; ni < 2; ++ni)
                acc[MH*4 + mi][NH*2 + ni] = __builtin_amdgcn_mfma_f32_16x16x32_bf16(
                    a[mi][kk], b[ni][kk], acc[MH*4 + mi][NH*2 + ni], 0, 0, 0);
}

template<int MODE, int AMODE>
__global__ __launch_bounds__(512)
void gemm8(const short* __restrict__ Ab16, const float* __restrict__ Af32,
           const short* __restrict__ Bt,
           const float* __restrict__ bias, const short* __restrict__ resid,
           short* __restrict__ Cb, float* __restrict__ Cf)
{
    constexpr int K = 2048, N = 2048;
    constexpr int NT = K >> 6;            // 32 K-tiles
    constexpr int NP = (NT >> 1) - 1;     // 15 full iterations
    __shared__ __align__(16) short lds[2][2][256 * 64];
    const int tid = threadIdx.x;

    // r6 XCD swizzle (proven; r10's "natural" map doubled FETCH)
    constexpr int cpx = 128;
    const int wg  = ((int)blockIdx.x & 7) * cpx + ((int)blockIdx.x >> 3);
    const int tm  = wg >> 3, tn = wg & 7;

    const int wave = tid >> 6, lane = tid & 63;
    const int wm = wave >> 2, wn = wave & 3;        // 2 x 4 wave grid, 128x64 out each
    const int lrow = lane & 15, lgrp = lane >> 4;

    const short* Bb = Bt + (size_t)tn * 256 * K;

    // ---- staging thread mapping ----
    const int r0 = tid >> 3, c0 = tid & 7;
    const int cg = c0 ^ (r0 & 7);                   // inverse swizzle (gload_lds source)
    constexpr size_t DL  = (size_t)128 * K;
    constexpr int    DLD = 128 * 64;
    const int rB = ((r0 >> 5) << 6) | (r0 & 31);

    const short* pB0 = Bb + (size_t)rB * K + cg * 8;
    const short* pB1 = Bb + (size_t)(rB + 32) * K + cg * 8;

    short* base = &lds[0][0][0];
    int oB0 = 16384 + rB * 64 + c0 * 8;
    int oB1 = 16384 + (rB + 32) * 64 + c0 * 8;

    auto stB0 = [&]{ load_lds16(pB0, base + oB0); load_lds16(pB0 + DL, base + oB0 + DLD); pB0 += 64; oB0 ^= 32768; };
    auto stB1 = [&]{ load_lds16(pB1, base + oB1); load_lds16(pB1 + DL, base + oB1 + DLD); pB1 += 64; oB1 ^= 32768; };

    // ---- fragment reads ----
    bf16x8 a[4][2], b0[2][2], b1[2][2];
    const int sw0 = (lgrp ^ (lrow & 7)) * 8;
    const int sw1 = ((4 + lgrp) ^ (lrow & 7)) * 8;

    auto readA = [&](int buf, int mh) {
        const short* s = &lds[buf][0][0];
        int bb = (wm * 128 + mh * 64 + lrow) * 64;
        #pragma unroll
        for (int mi = 0; mi < 4; ++mi) {
            a[mi][0] = *(const bf16x8*)&s[bb + mi * 1024 + sw0];
            a[mi][1] = *(const bf16x8*)&s[bb + mi * 1024 + sw1];
        }
    };
    auto readB = [&](int buf, int nh, bf16x8 (&b)[2][2]) {
        const short* s = &lds[buf][1][0];
        int bb = (wn * 64 + nh * 32 + lrow) * 64;
        #pragma unroll
        for (int ni = 0; ni < 2; ++ni) {
            b[ni][0] = *(const bf16x8*)&s[bb + ni * 1024 + sw0];
            b[ni][1] = *(const bf16x8*)&s[bb + ni * 1024 + sw1];
        }
    };

    f32x4 acc[8][4] = {};

    if constexpr (AMODE == 0) {
        // ======== exact r6 path: A bf16 via gload_lds ========
        const short* Ab = Ab16 + (size_t)tm * 256 * K;
        const short* pA0 = Ab + (size_t)r0 * K + cg * 8;
        const short* pA1 = Ab + (size_t)(64 + r0) * K + cg * 8;
        int oA0 = r0 * 64 + c0 * 8;
        int oA1 = (64 + r0) * 64 + c0 * 8;
        auto stA0 = [&]{ load_lds16(pA0, base + oA0); load_lds16(pA0 + DL, base + oA0 + DLD); pA0 += 64; oA0 ^= 32768; };
        auto stA1 = [&]{ load_lds16(pA1, base + oA1); load_lds16(pA1 + DL, base + oA1 + DLD); pA1 += 64; oA1 ^= 32768; };

        stA0(); stB0(); stB1(); stA1();
        stA0(); stB0(); stB1();

        for (int j = 0; j < NP; ++j) {
            VMCNT(6); BARX;
            stA1();
            readA(0, 0); readB(0, 0, b0);
            SP1; quadf<0,0>(acc, a, b0); SP0;
            BARX;
            stA0();
            readB(0, 1, b1);
            SP1; quadf<0,1>(acc, a, b1); SP0;
            BARX;
            stB0();
            readA(0, 1);
            SP1; quadf<1,0>(acc, a, b0); SP0;
            BARX;
            stB1();
            SP1; quadf<1,1>(acc, a, b1); SP0;
            VMCNT(6); BARX;
            stA1();
            readA(1, 0); readB(1, 0, b0);
            SP1; quadf<0,0>(acc, a, b0); SP0;
            BARX;
            stA0();
            readB(1, 1, b1);
            SP1; quadf<0,1>(acc, a, b1); SP0;
            BARX;
            stB0();
            readA(1, 1);
            SP1; quadf<1,0>(acc, a, b0); SP0;
            BARX;
            stB1();
            SP1; quadf<1,1>(acc, a, b1); SP0;
        }

        VMCNT(6); BARX;
        stA1();
        readA(0, 0); readB(0, 0, b0);
        SP1; quadf<0,0>(acc, a, b0); SP0;
        readB(0, 1, b1);
        quadf<0,1>(acc, a, b1);
        readA(0, 1);
        quadf<1,0>(acc, a, b0);
        quadf<1,1>(acc, a, b1);
        VMCNT(0); BARX;
        readA(1, 0); readB(1, 0, b0);
        quadf<0,0>(acc, a, b0);
        readB(1, 1, b1);
        quadf<0,1>(acc, a, b1);
        readA(1, 1);
        quadf<1,0>(acc, a, b0);
        quadf<1,1>(acc, a, b1);
    } else {
        // ======== A fp32 reg-staged (fused convert) ========
        const float* fA = Af32 + (size_t)tm * 256 * K;
        const float* pfA0 = fA + (size_t)r0 * K + c0 * 8;
        const float* pfA1 = fA + (size_t)(64 + r0) * K + c0 * 8;
        constexpr size_t DLf = (size_t)128 * K;
        int woA0 = r0 * 64 + (c0 ^ (r0 & 7)) * 8;          // swizzled write slot
        int woA1 = (64 + r0) * 64 + (c0 ^ (r0 & 7)) * 8;   // (64+r0)&7 == r0&7

        float4 rA0e[4], rA0o[4], rA1[4];
        auto ldA0 = [&](float4* d) {
            d[0] = *(const float4*)pfA0;       d[1] = *(const float4*)(pfA0 + 4);
            d[2] = *(const float4*)(pfA0+DLf); d[3] = *(const float4*)(pfA0 + DLf + 4);
            pfA0 += 64;
        };
        auto ldA1 = [&](float4* d) {
            d[0] = *(const float4*)pfA1;       d[1] = *(const float4*)(pfA1 + 4);
            d[2] = *(const float4*)(pfA1+DLf); d[3] = *(const float4*)(pfA1 + DLf + 4);
            pfA1 += 64;
        };
        auto wrA0 = [&](const float4* d) {
            *(bf16x8*)(base + woA0)       = pack8(d[0], d[1]);
            *(bf16x8*)(base + woA0 + DLD) = pack8(d[2], d[3]);
            woA0 ^= 32768;
        };
        auto wrA1 = [&](const float4* d) {
            *(bf16x8*)(base + woA1)       = pack8(d[0], d[1]);
            *(bf16x8*)(base + woA1 + DLD) = pack8(d[2], d[3]);
            woA1 ^= 32768;
        };

        // prologue: tile0 {A0,A1 regs; B0,B1 gl}, tile1 {A0 regs; B0,B1 gl} = 20 loads
        ldA0(rA0e); ldA1(rA1); stB0(); stB1();
        ldA0(rA0o); stB0(); stB1();
        VMCNT(8);                               // land tile0's 12 oldest
        wrA0(rA0e); wrA1(rA1); LGKMF;

        for (int j = 0; j < NP; ++j) {
            // ph0 (publish buf0 = tile 2j)
            BARX;
            ldA1(rA1);                          // A1(2j+1)
            readA(0, 0); readB(0, 0, b0);
            SP1; quadf<0,0>(acc, a, b0); SP0;
            // ph1
            BARX;
            ldA0(rA0e);                         // A0(2j+2)
            readB(0, 1, b1);
            SP1; quadf<0,1>(acc, a, b1); SP0;
            // ph2
            BARX;
            stB0();                             // B0(2j+2)
            readA(0, 1);
            SP1; quadf<1,0>(acc, a, b0); SP0;
            // ph3: land tile 2j+1 (A regs + B gloads), write its A
            BARX;
            VMCNT(6);
            wrA0(rA0o); wrA1(rA1);              // A(2j+1) -> buf1
            stB1();                             // B1(2j+2)
            SP1; quadf<1,1>(acc, a, b1); SP0;
            LGKMF;
            // ph4 (publish buf1 = tile 2j+1)
            BARX;
            ldA1(rA1);                          // A1(2j+2)
            readA(1, 0); readB(1, 0, b0);
            SP1; quadf<0,0>(acc, a, b0); SP0;
            // ph5
            BARX;
            ldA0(rA0o);                         // A0(2j+3)
            readB(1, 1, b1);
            SP1; quadf<0,1>(acc, a, b1); SP0;
            // ph6
            BARX;
            stB0();                             // B0(2j+3)
            readA(1, 1);
            SP1; quadf<1,0>(acc, a, b0); SP0;
            // ph7: land tile 2j+2, write its A
            BARX;
            VMCNT(6);
            wrA0(rA0e); wrA1(rA1);              // A(2j+2) -> buf0
            stB1();                             // B1(2j+3)
            SP1; quadf<1,1>(acc, a, b1); SP0;
            LGKMF;
        }

        // epilogue: buf0 = tile 30 (ready); in flight: A0(31) regs + B0,B1(31)
        BARX;                                   // publish tile 30
        ldA1(rA1);                              // A1(31)
        readA(0, 0); readB(0, 0, b0);
        SP1; quadf<0,0>(acc, a, b0); SP0;
        BARX;
        readB(0, 1, b1);
        SP1; quadf<0,1>(acc, a, b1); SP0;
        BARX;
        readA(0, 1);
        SP1; quadf<1,0>(acc, a, b0); SP0;
        BARX;
        VMCNT(0);
        wrA0(rA0o); wrA1(rA1);                  // A(31) -> buf1
        SP1; quadf<1,1>(acc, a, b1); SP0;
        LGKMF;
        BARX;                                   // publish tile 31
        readA(1, 0); readB(1, 0, b0);
        quadf<0,0>(acc, a, b0);
        readB(1, 1, b1);
        quadf<0,1>(acc, a, b1);
        readA(1, 1);
        quadf<1,0>(acc, a, b0);
        quadf<1,1>(acc, a, b1);
    }

    // C write
    #pragma unroll
    for (int m = 0; m < 8; ++m) {
        #pragma unroll
        for (int n = 0; n < 4; ++n) {
            const int col = tn * 256 + wn * 64 + n * 16 + lrow;
            const float bv = bias[col];
            #pragma unroll
            for (int r = 0; r < 4; ++r) {
                const int row = tm * 256 + wm * 128 + m * 16 + lgrp * 4 + r;
                float v = acc[m][n][r] + bv;
                if (MODE == 0) {
                    Cb[(size_t)row * N + col] = f2bf(v);
                } else {
                    v += bf2f(resid[(size_t)row * N + col]);
                    Cf[(size_t)row * N + col] = v;
                }
            }
        }
    }
}

// ---------- per-sample 16-head cosine attention (bf16 in), transposed bf16 out ----------
#define PAD 132

__global__ __launch_bounds__(256)
void attn(const short* __restrict__ qp, const short* __restrict__ kp,
          const short* __restrict__ vp, short* __restrict__ ot)
{
    __shared__ __align__(16) float qs[HNUM * PAD];
    __shared__ __align__(16) float ks[HNUM * PAD];
    __shared__ __align__(16) float vs[HNUM * PAD];
    __shared__ float rq[HNUM], rk[HNUM], sm[HNUM * 17];

    const int b = blockIdx.x;
    const int tid = threadIdx.x;
    const short* qr = qp + (size_t)b * DDIM;
    const short* kr = kp + (size_t)b * DDIM;
    const short* vr = vp + (size_t)b * DDIM;

    {
        int e = tid * 8;
        int h = e >> 7, d = e & 127;
        union { bf16x8 v; short s[8]; } u;
        float4 f0, f1;
        u.v = *(const bf16x8*)(qr + e);
        f0.x = bf2f(u.s[0]); f0.y = bf2f(u.s[1]); f0.z = bf2f(u.s[2]); f0.w = bf2f(u.s[3]);
        f1.x = bf2f(u.s[4]); f1.y = bf2f(u.s[5]); f1.z = bf2f(u.s[6]); f1.w = bf2f(u.s[7]);
        *(float4*)&qs[h * PAD + d] = f0; *(float4*)&qs[h * PAD + d + 4] = f1;
        u.v = *(const bf16x8*)(kr + e);
        f0.x = bf2f(u.s[0]); f0.y = bf2f(u.s[1]); f0.z = bf2f(u.s[2]); f0.w = bf2f(u.s[3]);
        f1.x = bf2f(u.s[4]); f1.y = bf2f(u.s[5]); f1.z = bf2f(u.s[6]); f1.w = bf2f(u.s[7]);
        *(float4*)&ks[h * PAD + d] = f0; *(float4*)&ks[h * PAD + d + 4] = f1;
        u.v = *(const bf16x8*)(vr + e);
        f0.x = bf2f(u.s[0]); f0.y = bf2f(u.s[1]); f0.z = bf2f(u.s[2]); f0.w = bf2f(u.s[3]);
        f1.x = bf2f(u.s[4]); f1.y = bf2f(u.s[5]); f1.z = bf2f(u.s[6]); f1.w = bf2f(u.s[7]);
        *(float4*)&vs[h * PAD + d] = f0; *(float4*)&vs[h * PAD + d + 4] = f1;
    }
    __syncthreads();

    {
        int h = tid >> 4, p = tid & 15;
        float sq = 0.f, sk = 0.f;
        #pragma unroll
        for (int j = 0; j < 8; ++j) {
            float x = qs[h * PAD + p + 16 * j]; sq += x * x;
            float y = ks[h * PAD + p + 16 * j]; sk += y * y;
        }
        #pragma unroll
        for (int m = 1; m < 16; m <<= 1) {
            sq += __shfl_xor(sq, m);
            sk += __shfl_xor(sk, m);
        }
        if (p == 0) { rq[h] = rsqrtf(sq); rk[h] = rsqrtf(sk); }
    }
    __syncthreads();

    {
        int h = tid >> 4, g = tid & 15;
        float dot = 0.f;
        #pragma unroll
        for (int d = 0; d < HD; d += 4) {
            float4 q4 = *(const float4*)&qs[h * PAD + d];
            float4 k4 = *(const float4*)&ks[g * PAD + d];
            dot += q4.x * k4.x + q4.y * k4.y + q4.z * k4.z + q4.w * k4.w;
        }
        sm[h * 17 + g] = dot * rq[h] * rk[g] * (1.0f / 128.0f);
    }
    __syncthreads();

    {
        int h = tid & 15, u = tid >> 4;
        float o[8] = {};
        #pragma unroll
        for (int g = 0; g < 16; ++g) {
            float s = sm[h * 17 + g];
            #pragma unroll
            for (int i = 0; i < 8; ++i)
                o[i] = fmaf(s, vs[g * PAD + u + 16 * i], o[i]);
        }
        #pragma unroll
        for (int i = 0; i < 8; ++i)
            ot[(size_t)b * DDIM + u * 16 + 256 * i + h] = f2bf(o[i]);
    }
}

// ---------- in-place row LayerNorm ----------
__global__ __launch_bounds__(256)
void lnorm(float* __restrict__ x, const float* __restrict__ gamma, const float* __restrict__ beta)
{
    const int row = blockIdx.x;
    const int tid = threadIdx.x;
    float* xr = x + (size_t)row * DDIM;

    float4 v0 = *(const float4*)(xr + tid * 4);
    float4 v1 = *(const float4*)(xr + 1024 + tid * 4);
    float s  = v0.x + v0.y + v0.z + v0.w + v1.x + v1.y + v1.z + v1.w;
    float s2 = v0.x*v0.x + v0.y*v0.y + v0.z*v0.z + v0.w*v0.w
             + v1.x*v1.x + v1.y*v1.y + v1.z*v1.z + v1.w*v1.w;

    #pragma unroll
    for (int m = 1; m < 64; m <<= 1) {
        s  += __shfl_xor(s, m);
        s2 += __shfl_xor(s2, m);
    }
    __shared__ float ws1[4], ws2[4];
    if ((tid & 63) == 0) { ws1[tid >> 6] = s; ws2[tid >> 6] = s2; }
    __syncthreads();
    s  = ws1[0] + ws1[1] + ws1[2] + ws1[3];
    s2 = ws2[0] + ws2[1] + ws2[2] + ws2[3];

    const float mu  = s * (1.0f / DDIM);
    const float var = s2 * (1.0f / DDIM) - mu * mu;
    const float rstd = rsqrtf(var + 1e-5f);

    float4 g0 = *(const float4*)(gamma + tid * 4);
    float4 g1 = *(const float4*)(gamma + 1024 + tid * 4);
    float4 b0 = *(const float4*)(beta + tid * 4);
    float4 b1 = *(const float4*)(beta + 1024 + tid * 4);

    v0.x = (v0.x - mu) * rstd * g0.x + b0.x;
    v0.y = (v0.y - mu) * rstd * g0.y + b0.y;
    v0.z = (v0.z - mu) * rstd * g0.z + b0.z;
    v0.w = (v0.w - mu) * rstd * g0.w + b0.w;
    v1.x = (v1.x - mu) * rstd * g1.x + b1.x;
    v1.y = (v1.y - mu) * rstd * g1.y + b1.y;
    v1.z = (v1.z - mu) * rstd * g1.z + b1.z;
    v1.w = (v1.w - mu) * rstd * g1.w + b1.w;

    *(float4*)(xr + tid * 4) = v0;
    *(float4*)(xr + 1024 + tid * 4) = v1;
}

// ---------- launch ----------
extern "C" void kernel_launch(void* const* d_in, const int* in_sizes, int n_in,
                              void* d_out, int out_size, void* d_ws, size_t ws_size,
                              hipStream_t stream)
{
    const float* q     = (const float*)d_in[0];
    const float* k     = (const float*)d_in[1];
    const float* v     = (const float*)d_in[2];
    const float* Wq    = (const float*)d_in[3];
    const float* bq    = (const float*)d_in[4];
    const float* Wk    = (const float*)d_in[5];
    const float* bk    = (const float*)d_in[6];
    const float* Wv    = (const float*)d_in[7];
    const float* bv    = (const float*)d_in[8];
    const float* Wo    = (const float*)d_in[9];
    const float* bo    = (const float*)d_in[10];
    const float* gamma = (const float*)d_in[11];
    const float* beta  = (const float*)d_in[12];

    const size_t BD = (size_t)BDIM * DDIM;
    char* ws = (char*)d_ws;
    size_t off = 0;
    auto alloc = [&](size_t bytes) { void* p = ws + off; off += (bytes + 255) & ~(size_t)255; return p; };

    short* Wqt = (short*)alloc((size_t)DDIM * DDIM * 2);
    short* Wkt = (short*)alloc((size_t)DDIM * DDIM * 2);
    short* Wvt = (short*)alloc((size_t)DDIM * DDIM * 2);
    short* Wot = (short*)alloc((size_t)DDIM * DDIM * 2);
    short* xb  = (short*)alloc(BD * 2);   // attn output (bf16)
    short* qpb = (short*)alloc(BD * 2);   // bf16 q-projection (attn input + residual)
    short* kpb = (short*)alloc(BD * 2);
    short* vpb = (short*)alloc(BD * 2);
    float* xout = (float*)d_out;

    wtrans<<<dim3(DDIM / 32, DDIM / 32, 4), dim3(32, 8), 0, stream>>>(Wq, Wk, Wv, Wo, Wqt, Wkt, Wvt, Wot);

    const int grid = (BDIM / 256) * (DDIM / 256);   // 1024

    gemm8<0,1><<<grid, 512, 0, stream>>>(nullptr, q, Wqt, bq, nullptr, qpb, nullptr);
    gemm8<0,1><<<grid, 512, 0, stream>>>(nullptr, k, Wkt, bk, nullptr, kpb, nullptr);
    gemm8<0,1><<<grid, 512, 0, stream>>>(nullptr, v, Wvt, bv, nullptr, vpb, nullptr);

    attn<<<BDIM, 256, 0, stream>>>(qpb, kpb, vpb, xb);

    gemm8<1,0><<<grid, 512, 0, stream>>>(xb, nullptr, Wot, bo, qpb, nullptr, xout);

    lnorm<<<BDIM, 256, 0, stream>>>(xout, gamma, beta);
}

// Round 12
// 1700.265 us; speedup vs baseline: 1.3774x; 1.3774x over previous
//
#include <hip/hip_runtime.h>

typedef __attribute__((ext_vector_type(8))) short bf16x8;
typedef __attribute__((ext_vector_type(4))) float f32x4;

#define BDIM 32768
#define DDIM 2048
#define HNUM 16
#define HD   128

// ---------- helpers ----------
__device__ inline short f2bf(float f) {
    union { float f; unsigned u; } v; v.f = f;
    unsigned r = v.u + 0x7FFFu + ((v.u >> 16) & 1u);   // round-to-nearest-even
    return (short)(r >> 16);
}
__device__ inline float bf2f(short s) {
    union { unsigned u; float f; } v; v.u = ((unsigned)(unsigned short)s) << 16; return v.f;
}

__device__ inline void load_lds16(const void* g, void* l) {
    __builtin_amdgcn_global_load_lds(
        (const __attribute__((address_space(1))) void*)g,
        (__attribute__((address_space(3))) void*)l, 16, 0, 0);
}

#define VMCNT(n) asm volatile("s_waitcnt vmcnt(" #n ")" ::: "memory")
#define BARX     do { __builtin_amdgcn_s_barrier(); __builtin_amdgcn_sched_barrier(0); } while (0)
#define SP1      __builtin_amdgcn_s_setprio(1)
#define SP0      __builtin_amdgcn_s_setprio(0)

// ---------- fp32 -> bf16 convert ----------
__global__ __launch_bounds__(256)
void cvt1(const float* __restrict__ in, short* __restrict__ out, int n8)
{
    int idx = blockIdx.x * 256 + threadIdx.x;
    int stride = gridDim.x * 256;
    for (int ch = idx; ch < n8; ch += stride) {
        const float4* p = (const float4*)(in + (size_t)ch * 8);
        float4 x0 = p[0], x1 = p[1];
        union { bf16x8 v; short s[8]; } o;
        o.s[0] = f2bf(x0.x); o.s[1] = f2bf(x0.y); o.s[2] = f2bf(x0.z); o.s[3] = f2bf(x0.w);
        o.s[4] = f2bf(x1.x); o.s[5] = f2bf(x1.y); o.s[6] = f2bf(x1.z); o.s[7] = f2bf(x1.w);
        *(bf16x8*)(out + (size_t)ch * 8) = o.v;
    }
}

// ---------- weight transpose + convert: W[K][N] fp32 -> Wt[N][K] bf16 ----------
__global__ __launch_bounds__(256)
void wtrans(const float* __restrict__ w0, const float* __restrict__ w1,
            const float* __restrict__ w2, const float* __restrict__ w3,
            short* __restrict__ o0, short* __restrict__ o1,
            short* __restrict__ o2, short* __restrict__ o3)
{
    const float* W = blockIdx.z == 0 ? w0 : blockIdx.z == 1 ? w1 : blockIdx.z == 2 ? w2 : w3;
    short*       O = blockIdx.z == 0 ? o0 : blockIdx.z == 1 ? o1 : blockIdx.z == 2 ? o2 : o3;
    __shared__ float t[32][33];
    int bx = blockIdx.x * 32;   // n
    int by = blockIdx.y * 32;   // k
    int tx = threadIdx.x, ty = threadIdx.y;  // 32 x 8
    #pragma unroll
    for (int r = 0; r < 4; ++r)
        t[ty + 8*r][tx] = W[(size_t)(by + ty + 8*r) * DDIM + bx + tx];
    __syncthreads();
    #pragma unroll
    for (int r = 0; r < 4; ++r)
        O[(size_t)(bx + ty + 8*r) * DDIM + by + tx] = f2bf(t[tx][ty + 8*r]);
}

// ---------- 128x128 4-wave bf16 GEMM, 64KB LDS -> 2 blocks/CU ----------
// Orthogonal attack on the r6 plateau (MfmaUtil 41% at 1 block/CU): smaller
// tile halves LDS so TWO blocks co-reside per CU -- when one block stalls at
// its barrier/vmcnt, the other keeps the MFMA pipe fed (m114 overlap).
// Loose double-buffered loop: per K-tile { vmcnt(8); BAR; 16 ds_read; 32 MFMA;
// BAR; stage tile j+2 (8 gload_lds) }. Same swizzle/fragment code as r6.

template<int MODE>
__global__ __launch_bounds__(256, 2)
void gemm4w(const short* __restrict__ A, const short* __restrict__ Bt,
            const float* __restrict__ bias, const short* __restrict__ resid,
            short* __restrict__ Cb, float* __restrict__ Cf)
{
    constexpr int K = 2048, N = 2048;
    constexpr int NT = K >> 6;            // 32 K-tiles
    __shared__ __align__(16) short lds[2][2][128 * 64];   // 64 KB
    const int tid = threadIdx.x;

    // XCD swizzle (r6-proven form): nwg = 4096, cpx = 512
    constexpr int cpx = 512;
    const int wg  = ((int)blockIdx.x & 7) * cpx + ((int)blockIdx.x >> 3);
    const int tm  = wg >> 4, tn = wg & 15;

    const int wave = tid >> 6, lane = tid & 63;
    const int wm = wave >> 1, wn = wave & 1;        // 2 x 2 wave grid, 64x64 out each
    const int lrow = lane & 15, lgrp = lane >> 4;

    const short* Ab = A  + (size_t)tm * 128 * K;
    const short* Bb = Bt + (size_t)tn * 128 * K;

    // ---- staging: thread -> 4 chunks/tile/stream; row = r0 + 32*l ----
    const int r0 = tid >> 3, c0 = tid & 7;          // r0: 0..31
    const int cg = c0 ^ (r0 & 7);                   // inverse swizzle on source
    constexpr size_t DS  = (size_t)32 * K;          // per-l global step
    constexpr int    DLD = 32 * 64;                 // per-l LDS step

    const short* pA = Ab + (size_t)r0 * K + cg * 8;
    const short* pB = Bb + (size_t)r0 * K + cg * 8;

    short* base = &lds[0][0][0];
    int oA = r0 * 64 + c0 * 8;                      // lds[buf][0]
    int oB = 8192 + r0 * 64 + c0 * 8;               // lds[buf][1]

    auto stA = [&]{
        #pragma unroll
        for (int l = 0; l < 4; ++l)
            load_lds16(pA + l * DS, base + oA + l * DLD);
        pA += 64; oA ^= 16384;
    };
    auto stB = [&]{
        #pragma unroll
        for (int l = 0; l < 4; ++l)
            load_lds16(pB + l * DS, base + oB + l * DLD);
        pB += 64; oB ^= 16384;
    };

    // ---- fragment reads (compiler inserts counted lgkmcnt before MFMA) ----
    bf16x8 a[4][2], b[4][2];
    const int sw0 = (lgrp ^ (lrow & 7)) * 8;
    const int sw1 = ((4 + lgrp) ^ (lrow & 7)) * 8;

    auto readA = [&](int buf) {
        const short* s = &lds[buf][0][0];
        int bb = (wm * 64 + lrow) * 64;
        #pragma unroll
        for (int mi = 0; mi < 4; ++mi) {
            a[mi][0] = *(const bf16x8*)&s[bb + mi * 1024 + sw0];
            a[mi][1] = *(const bf16x8*)&s[bb + mi * 1024 + sw1];
        }
    };
    auto readB = [&](int buf) {
        const short* s = &lds[buf][1][0];
        int bb = (wn * 64 + lrow) * 64;
        #pragma unroll
        for (int ni = 0; ni < 4; ++ni) {
            b[ni][0] = *(const bf16x8*)&s[bb + ni * 1024 + sw0];
            b[ni][1] = *(const bf16x8*)&s[bb + ni * 1024 + sw1];
        }
    };

    f32x4 acc[4][4] = {};

    auto mfma32 = [&]{
        #pragma unroll
        for (int kk = 0; kk < 2; ++kk)
            #pragma unroll
            for (int mi = 0; mi < 4; ++mi)
                #pragma unroll
                for (int ni = 0; ni < 4; ++ni)
                    acc[mi][ni] = __builtin_amdgcn_mfma_f32_16x16x32_bf16(
                        a[mi][kk], b[ni][kk], acc[mi][ni], 0, 0, 0);
    };

    // prologue: tile0 -> buf0, tile1 -> buf1 (16 loads in flight)
    stA(); stB();
    stA(); stB();

    for (int j = 0; j < NT - 2; ++j) {
        VMCNT(8); BARX;                   // tile j landed; published
        readA(j & 1); readB(j & 1);
        SP1; mfma32(); SP0;
        BARX;                             // all reads of buf j&1 done
        stA(); stB();                     // tile j+2 -> buf j&1
    }
    // j = NT-2 (buf0): in flight tiles NT-2, NT-1
    VMCNT(8); BARX;
    readA(0); readB(0);
    SP1; mfma32(); SP0;
    // j = NT-1 (buf1)
    VMCNT(0); BARX;
    readA(1); readB(1);
    mfma32();

    // ---- C write ----
    #pragma unroll
    for (int m = 0; m < 4; ++m) {
        #pragma unroll
        for (int n = 0; n < 4; ++n) {
            const int col = tn * 128 + wn * 64 + n * 16 + lrow;
            const float bv = bias[col];
            #pragma unroll
            for (int r = 0; r < 4; ++r) {
                const int row = tm * 128 + wm * 64 + m * 16 + lgrp * 4 + r;
                float v = acc[m][n][r] + bv;
                if (MODE == 0) {
                    Cb[(size_t)row * N + col] = f2bf(v);
                } else {
                    v += bf2f(resid[(size_t)row * N + col]);
                    Cf[(size_t)row * N + col] = v;
                }
            }
        }
    }
}

// ---------- per-sample 16-head cosine attention (bf16 in), transposed bf16 out ----------
#define PAD 132

__global__ __launch_bounds__(256)
void attn(const short* __restrict__ qp, const short* __restrict__ kp,
          const short* __restrict__ vp, short* __restrict__ ot)
{
    __shared__ __align__(16) float qs[HNUM * PAD];
    __shared__ __align__(16) float ks[HNUM * PAD];
    __shared__ __align__(16) float vs[HNUM * PAD];
    __shared__ float rq[HNUM], rk[HNUM], sm[HNUM * 17];

    const int b = blockIdx.x;
    const int tid = threadIdx.x;
    const short* qr = qp + (size_t)b * DDIM;
    const short* kr = kp + (size_t)b * DDIM;
    const short* vr = vp + (size_t)b * DDIM;

    {
        int e = tid * 8;
        int h = e >> 7, d = e & 127;
        union { bf16x8 v; short s[8]; } u;
        float4 f0, f1;
        u.v = *(const bf16x8*)(qr + e);
        f0.x = bf2f(u.s[0]); f0.y = bf2f(u.s[1]); f0.z = bf2f(u.s[2]); f0.w = bf2f(u.s[3]);
        f1.x = bf2f(u.s[4]); f1.y = bf2f(u.s[5]); f1.z = bf2f(u.s[6]); f1.w = bf2f(u.s[7]);
        *(float4*)&qs[h * PAD + d] = f0; *(float4*)&qs[h * PAD + d + 4] = f1;
        u.v = *(const bf16x8*)(kr + e);
        f0.x = bf2f(u.s[0]); f0.y = bf2f(u.s[1]); f0.z = bf2f(u.s[2]); f0.w = bf2f(u.s[3]);
        f1.x = bf2f(u.s[4]); f1.y = bf2f(u.s[5]); f1.z = bf2f(u.s[6]); f1.w = bf2f(u.s[7]);
        *(float4*)&ks[h * PAD + d] = f0; *(float4*)&ks[h * PAD + d + 4] = f1;
        u.v = *(const bf16x8*)(vr + e);
        f0.x = bf2f(u.s[0]); f0.y = bf2f(u.s[1]); f0.z = bf2f(u.s[2]); f0.w = bf2f(u.s[3]);
        f1.x = bf2f(u.s[4]); f1.y = bf2f(u.s[5]); f1.z = bf2f(u.s[6]); f1.w = bf2f(u.s[7]);
        *(float4*)&vs[h * PAD + d] = f0; *(float4*)&vs[h * PAD + d + 4] = f1;
    }
    __syncthreads();

    {
        int h = tid >> 4, p = tid & 15;
        float sq = 0.f, sk = 0.f;
        #pragma unroll
        for (int j = 0; j < 8; ++j) {
            float x = qs[h * PAD + p + 16 * j]; sq += x * x;
            float y = ks[h * PAD + p + 16 * j]; sk += y * y;
        }
        #pragma unroll
        for (int m = 1; m < 16; m <<= 1) {
            sq += __shfl_xor(sq, m);
            sk += __shfl_xor(sk, m);
        }
        if (p == 0) { rq[h] = rsqrtf(sq); rk[h] = rsqrtf(sk); }
    }
    __syncthreads();

    {
        int h = tid >> 4, g = tid & 15;
        float dot = 0.f;
        #pragma unroll
        for (int d = 0; d < HD; d += 4) {
            float4 q4 = *(const float4*)&qs[h * PAD + d];
            float4 k4 = *(const float4*)&ks[g * PAD + d];
            dot += q4.x * k4.x + q4.y * k4.y + q4.z * k4.z + q4.w * k4.w;
        }
        sm[h * 17 + g] = dot * rq[h] * rk[g] * (1.0f / 128.0f);
    }
    __syncthreads();

    {
        int h = tid & 15, u = tid >> 4;
        float o[8] = {};
        #pragma unroll
        for (int g = 0; g < 16; ++g) {
            float s = sm[h * 17 + g];
            #pragma unroll
            for (int i = 0; i < 8; ++i)
                o[i] = fmaf(s, vs[g * PAD + u + 16 * i], o[i]);
        }
        #pragma unroll
        for (int i = 0; i < 8; ++i)
            ot[(size_t)b * DDIM + u * 16 + 256 * i + h] = f2bf(o[i]);
    }
}

// ---------- in-place row LayerNorm ----------
__global__ __launch_bounds__(256)
void lnorm(float* __restrict__ x, const float* __restrict__ gamma, const float* __restrict__ beta)
{
    const int row = blockIdx.x;
    const int tid = threadIdx.x;
    float* xr = x + (size_t)row * DDIM;

    float4 v0 = *(const float4*)(xr + tid * 4);
    float4 v1 = *(const float4*)(xr + 1024 + tid * 4);
    float s  = v0.x + v0.y + v0.z + v0.w + v1.x + v1.y + v1.z + v1.w;
    float s2 = v0.x*v0.x + v0.y*v0.y + v0.z*v0.z + v0.w*v0.w
             + v1.x*v1.x + v1.y*v1.y + v1.z*v1.z + v1.w*v1.w;

    #pragma unroll
    for (int m = 1; m < 64; m <<= 1) {
        s  += __shfl_xor(s, m);
        s2 += __shfl_xor(s2, m);
    }
    __shared__ float ws1[4], ws2[4];
    if ((tid & 63) == 0) { ws1[tid >> 6] = s; ws2[tid >> 6] = s2; }
    __syncthreads();
    s  = ws1[0] + ws1[1] + ws1[2] + ws1[3];
    s2 = ws2[0] + ws2[1] + ws2[2] + ws2[3];

    const float mu  = s * (1.0f / DDIM);
    const float var = s2 * (1.0f / DDIM) - mu * mu;
    const float rstd = rsqrtf(var + 1e-5f);

    float4 g0 = *(const float4*)(gamma + tid * 4);
    float4 g1 = *(const float4*)(gamma + 1024 + tid * 4);
    float4 b0 = *(const float4*)(beta + tid * 4);
    float4 b1 = *(const float4*)(beta + 1024 + tid * 4);

    v0.x = (v0.x - mu) * rstd * g0.x + b0.x;
    v0.y = (v0.y - mu) * rstd * g0.y + b0.y;
    v0.z = (v0.z - mu) * rstd * g0.z + b0.z;
    v0.w = (v0.w - mu) * rstd * g0.w + b0.w;
    v1.x = (v1.x - mu) * rstd * g1.x + b1.x;
    v1.y = (v1.y - mu) * rstd * g1.y + b1.y;
    v1.z = (v1.z - mu) * rstd * g1.z + b1.z;
    v1.w = (v1.w - mu) * rstd * g1.w + b1.w;

    *(float4*)(xr + tid * 4) = v0;
    *(float4*)(xr + 1024 + tid * 4) = v1;
}

// ---------- launch ----------
extern "C" void kernel_launch(void* const* d_in, const int* in_sizes, int n_in,
                              void* d_out, int out_size, void* d_ws, size_t ws_size,
                              hipStream_t stream)
{
    const float* q     = (const float*)d_in[0];
    const float* k     = (const float*)d_in[1];
    const float* v     = (const float*)d_in[2];
    const float* Wq    = (const float*)d_in[3];
    const float* bq    = (const float*)d_in[4];
    const float* Wk    = (const float*)d_in[5];
    const float* bk    = (const float*)d_in[6];
    const float* Wv    = (const float*)d_in[7];
    const float* bv    = (const float*)d_in[8];
    const float* Wo    = (const float*)d_in[9];
    const float* bo    = (const float*)d_in[10];
    const float* gamma = (const float*)d_in[11];
    const float* beta  = (const float*)d_in[12];

    const size_t BD = (size_t)BDIM * DDIM;
    char* ws = (char*)d_ws;
    size_t off = 0;
    auto alloc = [&](size_t bytes) { void* p = ws + off; off += (bytes + 255) & ~(size_t)255; return p; };

    short* Wqt = (short*)alloc((size_t)DDIM * DDIM * 2);
    short* Wkt = (short*)alloc((size_t)DDIM * DDIM * 2);
    short* Wvt = (short*)alloc((size_t)DDIM * DDIM * 2);
    short* Wot = (short*)alloc((size_t)DDIM * DDIM * 2);
    short* xb  = (short*)alloc(BD * 2);   // bf16 conv buffer (q/k/v in turn), then attn out
    short* qpb = (short*)alloc(BD * 2);   // bf16 q-projection (attn input + residual)
    short* kpb = (short*)alloc(BD * 2);
    short* vpb = (short*)alloc(BD * 2);
    float* xout = (float*)d_out;

    wtrans<<<dim3(DDIM / 32, DDIM / 32, 4), dim3(32, 8), 0, stream>>>(Wq, Wk, Wv, Wo, Wqt, Wkt, Wvt, Wot);

    const int grid = (BDIM / 128) * (DDIM / 128);   // 4096
    const int n8 = (int)(BD / 8);

    cvt1<<<4096, 256, 0, stream>>>(q, xb, n8);
    gemm4w<0><<<grid, 256, 0, stream>>>(xb, Wqt, bq, nullptr, qpb, nullptr);
    cvt1<<<4096, 256, 0, stream>>>(k, xb, n8);
    gemm4w<0><<<grid, 256, 0, stream>>>(xb, Wkt, bk, nullptr, kpb, nullptr);
    cvt1<<<4096, 256, 0, stream>>>(v, xb, n8);
    gemm4w<0><<<grid, 256, 0, stream>>>(xb, Wvt, bv, nullptr, vpb, nullptr);

    attn<<<BDIM, 256, 0, stream>>>(qpb, kpb, vpb, xb);

    gemm4w<1><<<grid, 256, 0, stream>>>(xb, Wot, bo, qpb, nullptr, xout);

    lnorm<<<BDIM, 256, 0, stream>>>(xout, gamma, beta);
}

// Round 13
// 1444.252 us; speedup vs baseline: 1.6216x; 1.1773x over previous
//
#include <hip/hip_runtime.h>

typedef __attribute__((ext_vector_type(8))) short bf16x8;
typedef __attribute__((ext_vector_type(4))) float f32x4;

#define BDIM 32768
#define DDIM 2048
#define HNUM 16
#define HD   128

// ---------- helpers ----------
__device__ inline short f2bf(float f) {
    union { float f; unsigned u; } v; v.f = f;
    unsigned r = v.u + 0x7FFFu + ((v.u >> 16) & 1u);   // round-to-nearest-even
    return (short)(r >> 16);
}
__device__ inline float bf2f(short s) {
    union { unsigned u; float f; } v; v.u = ((unsigned)(unsigned short)s) << 16; return v.f;
}

__device__ inline void load_lds16(const void* g, void* l) {
    __builtin_amdgcn_global_load_lds(
        (const __attribute__((address_space(1))) void*)g,
        (__attribute__((address_space(3))) void*)l, 16, 0, 0);
}

#define VMCNT(n) asm volatile("s_waitcnt vmcnt(" #n ")" ::: "memory")
#define BARX     do { __builtin_amdgcn_s_barrier(); __builtin_amdgcn_sched_barrier(0); } while (0)
#define SP1      __builtin_amdgcn_s_setprio(1)
#define SP0      __builtin_amdgcn_s_setprio(0)

// ---------- fp32 -> bf16 convert (1 tensor) ----------
__global__ __launch_bounds__(256)
void cvt1(const float* __restrict__ in, short* __restrict__ out, int n8)
{
    int idx = blockIdx.x * 256 + threadIdx.x;
    int stride = gridDim.x * 256;
    for (int ch = idx; ch < n8; ch += stride) {
        const float4* p = (const float4*)(in + (size_t)ch * 8);
        float4 x0 = p[0], x1 = p[1];
        union { bf16x8 v; short s[8]; } o;
        o.s[0] = f2bf(x0.x); o.s[1] = f2bf(x0.y); o.s[2] = f2bf(x0.z); o.s[3] = f2bf(x0.w);
        o.s[4] = f2bf(x1.x); o.s[5] = f2bf(x1.y); o.s[6] = f2bf(x1.z); o.s[7] = f2bf(x1.w);
        *(bf16x8*)(out + (size_t)ch * 8) = o.v;
    }
}

// ---------- fp32 -> bf16 convert (3 tensors via z) ----------
__global__ __launch_bounds__(256)
void cvt3(const float* __restrict__ a, const float* __restrict__ b, const float* __restrict__ c,
          short* __restrict__ oa, short* __restrict__ ob, short* __restrict__ oc, int n8)
{
    const float* in  = blockIdx.z == 0 ? a  : (blockIdx.z == 1 ? b  : c);
    short*       out = blockIdx.z == 0 ? oa : (blockIdx.z == 1 ? ob : oc);
    int idx = blockIdx.x * 256 + threadIdx.x;
    int stride = gridDim.x * 256;
    for (int ch = idx; ch < n8; ch += stride) {
        const float4* p = (const float4*)(in + (size_t)ch * 8);
        float4 x0 = p[0], x1 = p[1];
        union { bf16x8 v; short s[8]; } o;
        o.s[0] = f2bf(x0.x); o.s[1] = f2bf(x0.y); o.s[2] = f2bf(x0.z); o.s[3] = f2bf(x0.w);
        o.s[4] = f2bf(x1.x); o.s[5] = f2bf(x1.y); o.s[6] = f2bf(x1.z); o.s[7] = f2bf(x1.w);
        *(bf16x8*)(out + (size_t)ch * 8) = o.v;
    }
}

// ---------- weight transpose + convert: W[K][N] fp32 -> Wt[N][K] bf16 ----------
__global__ __launch_bounds__(256)
void wtrans(const float* __restrict__ w0, const float* __restrict__ w1,
            const float* __restrict__ w2, const float* __restrict__ w3,
            short* __restrict__ o0, short* __restrict__ o1,
            short* __restrict__ o2, short* __restrict__ o3)
{
    const float* W = blockIdx.z == 0 ? w0 : blockIdx.z == 1 ? w1 : blockIdx.z == 2 ? w2 : w3;
    short*       O = blockIdx.z == 0 ? o0 : blockIdx.z == 1 ? o1 : blockIdx.z == 2 ? o2 : o3;
    __shared__ float t[32][33];
    int bx = blockIdx.x * 32;   // n
    int by = blockIdx.y * 32;   // k
    int tx = threadIdx.x, ty = threadIdx.y;  // 32 x 8
    #pragma unroll
    for (int r = 0; r < 4; ++r)
        t[ty + 8*r][tx] = W[(size_t)(by + ty + 8*r) * DDIM + bx + tx];
    __syncthreads();
    #pragma unroll
    for (int r = 0; r < 4; ++r)
        O[(size_t)(bx + ty + 8*r) * DDIM + by + tx] = f2bf(t[tx][ty + 8*r]);
}

// ---------- 256x256 8-wave 8-phase bf16 GEMM (r6, best measured: 291us) ----------
// One barrier per phase; NO asm lgkm waits (compiler emits counted lgkmcnt).
// vmcnt(6) only at buffer-switch phases. blockIdx.z selects among up to 3
// independent (A, Bt, bias, C) problem sets so the projections share one launch
// (tail-filling across the 3 GEMMs). MODE 0: bf16 out. MODE 1: f32 + resid.

template<int MODE>
__global__ __launch_bounds__(512)
void gemm8(const short* __restrict__ Aq, const short* __restrict__ Ak, const short* __restrict__ Av,
           const short* __restrict__ Btq, const short* __restrict__ Btk, const short* __restrict__ Btv,
           const float* __restrict__ biq, const float* __restrict__ bik, const float* __restrict__ biv,
           short* __restrict__ Cq, short* __restrict__ Ck, short* __restrict__ Cv,
           const short* __restrict__ resid, float* __restrict__ Cf)
{
    constexpr int K = 2048, N = 2048;
    constexpr int NT = K >> 6;            // 32 K-tiles
    constexpr int NP = (NT >> 1) - 1;     // 15 full iterations
    __shared__ __align__(16) short lds[2][2][256 * 64];
    const int tid = threadIdx.x;

    const int z = blockIdx.z;
    const short* A    = z == 0 ? Aq  : (z == 1 ? Ak  : Av);
    const short* Bt   = z == 0 ? Btq : (z == 1 ? Btk : Btv);
    const float* bias = z == 0 ? biq : (z == 1 ? bik : biv);
    short*       Cb   = z == 0 ? Cq  : (z == 1 ? Ck  : Cv);

    // r6 XCD swizzle (nwg=1024, cpx=128)
    constexpr int cpx = 128;
    const int wg  = ((int)blockIdx.x & 7) * cpx + ((int)blockIdx.x >> 3);
    const int tm  = wg >> 3, tn = wg & 7;

    const int wave = tid >> 6, lane = tid & 63;
    const int wm = wave >> 2, wn = wave & 3;        // 2 x 4 wave grid, 128x64 out each
    const int lrow = lane & 15, lgrp = lane >> 4;

    const short* Ab = A  + (size_t)tm * 256 * K;
    const short* Bb = Bt + (size_t)tn * 256 * K;

    // ---- staging streams: precomputed pointers + LDS offsets ----
    const int r0 = tid >> 3, c0 = tid & 7;
    const int cg = c0 ^ (r0 & 7);                   // inverse swizzle on source
    constexpr size_t DL  = (size_t)128 * K;         // second-load global delta
    constexpr int    DLD = 128 * 64;                // second-load LDS delta
    const int rB = ((r0 >> 5) << 6) | (r0 & 31);    // B row for B0 stream

    const short* pA0 = Ab + (size_t)r0 * K + cg * 8;
    const short* pA1 = Ab + (size_t)(64 + r0) * K + cg * 8;
    const short* pB0 = Bb + (size_t)rB * K + cg * 8;
    const short* pB1 = Bb + (size_t)(rB + 32) * K + cg * 8;

    short* base = &lds[0][0][0];
    int oA0 = r0 * 64 + c0 * 8;                     // into [buf][0]
    int oA1 = (64 + r0) * 64 + c0 * 8;
    int oB0 = 16384 + rB * 64 + c0 * 8;             // into [buf][1]
    int oB1 = 16384 + (rB + 32) * 64 + c0 * 8;

    auto stA0 = [&]{ load_lds16(pA0, base + oA0); load_lds16(pA0 + DL, base + oA0 + DLD); pA0 += 64; oA0 ^= 32768; };
    auto stA1 = [&]{ load_lds16(pA1, base + oA1); load_lds16(pA1 + DL, base + oA1 + DLD); pA1 += 64; oA1 ^= 32768; };
    auto stB0 = [&]{ load_lds16(pB0, base + oB0); load_lds16(pB0 + DL, base + oB0 + DLD); pB0 += 64; oB0 ^= 32768; };
    auto stB1 = [&]{ load_lds16(pB1, base + oB1); load_lds16(pB1 + DL, base + oB1 + DLD); pB1 += 64; oB1 ^= 32768; };

    // ---- fragment reads (compiler inserts counted lgkmcnt before MFMA uses) ----
    bf16x8 a[4][2], b0[2][2], b1[2][2];
    const int sw0 = (lgrp ^ (lrow & 7)) * 8;
    const int sw1 = ((4 + lgrp) ^ (lrow & 7)) * 8;

    auto readA = [&](int buf, int mh) {
        const short* s = &lds[buf][0][0];
        int bb = (wm * 128 + mh * 64 + lrow) * 64;
        #pragma unroll
        for (int mi = 0; mi < 4; ++mi) {
            a[mi][0] = *(const bf16x8*)&s[bb + mi * 1024 + sw0];
            a[mi][1] = *(const bf16x8*)&s[bb + mi * 1024 + sw1];
        }
    };
    auto readB = [&](int buf, int nh, bf16x8 (&b)[2][2]) {
        const short* s = &lds[buf][1][0];
        int bb = (wn * 64 + nh * 32 + lrow) * 64;
        #pragma unroll
        for (int ni = 0; ni < 2; ++ni) {
            b[ni][0] = *(const bf16x8*)&s[bb + ni * 1024 + sw0];
            b[ni][1] = *(const bf16x8*)&s[bb + ni * 1024 + sw1];
        }
    };

    auto quad00 = [&]{
        #pragma unroll
        for (int kk = 0; kk < 2; ++kk) ;
    };
    (void)quad00;

    f32x4 acc[8][4] = {};

    auto quadf = [&](int mh, bf16x8 (&b)[2][2], int nh) {
        #pragma unroll
        for (int kk = 0; kk < 2; ++kk)
            #pragma unroll
            for (int mi = 0; mi < 4; ++mi)
                #pragma unroll
                for (int ni = 0; ni < 2; ++ni)
                    acc[mh*4 + mi][nh*2 + ni] = __builtin_amdgcn_mfma_f32_16x16x32_bf16(
                        a[mi][kk], b[ni][kk], acc[mh*4 + mi][nh*2 + ni], 0, 0, 0);
    };

    // prologue: tile0 -> buf0 (A0,B0,B1,A1), tile1 -> buf1 (A0,B0,B1); 14 loads
    stA0(); stB0(); stB1(); stA1();
    stA0(); stB0(); stB1();

    for (int j = 0; j < NP; ++j) {
        // ph0 (buf0 = tile 2j): vmcnt(6) lands tile 2j
        VMCNT(6); BARX;
        stA1();                       // A1(2j+1) -> buf1
        readA(0, 0); readB(0, 0, b0);
        SP1; quadf(0, b0, 0); SP0;
        // ph1
        BARX;
        stA0();                       // A0(2j+2) -> buf0
        readB(0, 1, b1);
        SP1; quadf(0, b1, 1); SP0;
        // ph2
        BARX;
        stB0();                       // B0(2j+2) -> buf0
        readA(0, 1);
        SP1; quadf(1, b0, 0); SP0;
        // ph3 (register-held operands, no reads)
        BARX;
        stB1();                       // B1(2j+2) -> buf0
        SP1; quadf(1, b1, 1); SP0;
        // ph4 (buf1 = tile 2j+1): vmcnt(6) lands tile 2j+1
        VMCNT(6); BARX;
        stA1();                       // A1(2j+2) -> buf0
        readA(1, 0); readB(1, 0, b0);
        SP1; quadf(0, b0, 0); SP0;
        // ph5
        BARX;
        stA0();                       // A0(2j+3) -> buf1
        readB(1, 1, b1);
        SP1; quadf(0, b1, 1); SP0;
        // ph6
        BARX;
        stB0();                       // B0(2j+3) -> buf1
        readA(1, 1);
        SP1; quadf(1, b0, 0); SP0;
        // ph7
        BARX;
        stB1();                       // B1(2j+3) -> buf1
        SP1; quadf(1, b1, 1); SP0;
    }

    // epilogue: tiles NT-2 (buf0), NT-1 (buf1); only A1(NT-1) remains to stage
    VMCNT(6); BARX;
    stA1();                           // A1(NT-1) -> buf1
    readA(0, 0); readB(0, 0, b0);
    SP1; quadf(0, b0, 0); SP0;
    readB(0, 1, b1);
    quadf(0, b1, 1);
    readA(0, 1);
    quadf(1, b0, 0);
    quadf(1, b1, 1);
    VMCNT(0); BARX;                   // tile NT-1 fully landed
    readA(1, 0); readB(1, 0, b0);
    quadf(0, b0, 0);
    readB(1, 1, b1);
    quadf(0, b1, 1);
    readA(1, 1);
    quadf(1, b0, 0);
    quadf(1, b1, 1);

    // C write
    #pragma unroll
    for (int m = 0; m < 8; ++m) {
        #pragma unroll
        for (int n = 0; n < 4; ++n) {
            const int col = tn * 256 + wn * 64 + n * 16 + lrow;
            const float bv = bias[col];
            #pragma unroll
            for (int r = 0; r < 4; ++r) {
                const int row = tm * 256 + wm * 128 + m * 16 + lgrp * 4 + r;
                float v = acc[m][n][r] + bv;
                if (MODE == 0) {
                    Cb[(size_t)row * N + col] = f2bf(v);
                } else {
                    v += bf2f(resid[(size_t)row * N + col]);
                    Cf[(size_t)row * N + col] = v;
                }
            }
        }
    }
}

// ---------- per-sample 16-head cosine attention (bf16 in), transposed bf16 out ----------
#define PAD 132

__global__ __launch_bounds__(256)
void attn(const short* __restrict__ qp, const short* __restrict__ kp,
          const short* __restrict__ vp, short* __restrict__ ot)
{
    __shared__ __align__(16) float qs[HNUM * PAD];
    __shared__ __align__(16) float ks[HNUM * PAD];
    __shared__ __align__(16) float vs[HNUM * PAD];
    __shared__ float rq[HNUM], rk[HNUM], sm[HNUM * 17];

    const int b = blockIdx.x;
    const int tid = threadIdx.x;
    const short* qr = qp + (size_t)b * DDIM;
    const short* kr = kp + (size_t)b * DDIM;
    const short* vr = vp + (size_t)b * DDIM;

    {
        int e = tid * 8;
        int h = e >> 7, d = e & 127;
        union { bf16x8 v; short s[8]; } u;
        float4 f0, f1;
        u.v = *(const bf16x8*)(qr + e);
        f0.x = bf2f(u.s[0]); f0.y = bf2f(u.s[1]); f0.z = bf2f(u.s[2]); f0.w = bf2f(u.s[3]);
        f1.x = bf2f(u.s[4]); f1.y = bf2f(u.s[5]); f1.z = bf2f(u.s[6]); f1.w = bf2f(u.s[7]);
        *(float4*)&qs[h * PAD + d] = f0; *(float4*)&qs[h * PAD + d + 4] = f1;
        u.v = *(const bf16x8*)(kr + e);
        f0.x = bf2f(u.s[0]); f0.y = bf2f(u.s[1]); f0.z = bf2f(u.s[2]); f0.w = bf2f(u.s[3]);
        f1.x = bf2f(u.s[4]); f1.y = bf2f(u.s[5]); f1.z = bf2f(u.s[6]); f1.w = bf2f(u.s[7]);
        *(float4*)&ks[h * PAD + d] = f0; *(float4*)&ks[h * PAD + d + 4] = f1;
        u.v = *(const bf16x8*)(vr + e);
        f0.x = bf2f(u.s[0]); f0.y = bf2f(u.s[1]); f0.z = bf2f(u.s[2]); f0.w = bf2f(u.s[3]);
        f1.x = bf2f(u.s[4]); f1.y = bf2f(u.s[5]); f1.z = bf2f(u.s[6]); f1.w = bf2f(u.s[7]);
        *(float4*)&vs[h * PAD + d] = f0; *(float4*)&vs[h * PAD + d + 4] = f1;
    }
    __syncthreads();

    {
        int h = tid >> 4, p = tid & 15;
        float sq = 0.f, sk = 0.f;
        #pragma unroll
        for (int j = 0; j < 8; ++j) {
            float x = qs[h * PAD + p + 16 * j]; sq += x * x;
            float y = ks[h * PAD + p + 16 * j]; sk += y * y;
        }
        #pragma unroll
        for (int m = 1; m < 16; m <<= 1) {
            sq += __shfl_xor(sq, m);
            sk += __shfl_xor(sk, m);
        }
        if (p == 0) { rq[h] = rsqrtf(sq); rk[h] = rsqrtf(sk); }
    }
    __syncthreads();

    {
        int h = tid >> 4, g = tid & 15;
        float dot = 0.f;
        #pragma unroll
        for (int d = 0; d < HD; d += 4) {
            float4 q4 = *(const float4*)&qs[h * PAD + d];
            float4 k4 = *(const float4*)&ks[g * PAD + d];
            dot += q4.x * k4.x + q4.y * k4.y + q4.z * k4.z + q4.w * k4.w;
        }
        sm[h * 17 + g] = dot * rq[h] * rk[g] * (1.0f / 128.0f);
    }
    __syncthreads();

    {
        int h = tid & 15, u = tid >> 4;
        float o[8] = {};
        #pragma unroll
        for (int g = 0; g < 16; ++g) {
            float s = sm[h * 17 + g];
            #pragma unroll
            for (int i = 0; i < 8; ++i)
                o[i] = fmaf(s, vs[g * PAD + u + 16 * i], o[i]);
        }
        #pragma unroll
        for (int i = 0; i < 8; ++i)
            ot[(size_t)b * DDIM + u * 16 + 256 * i + h] = f2bf(o[i]);
    }
}

// ---------- in-place row LayerNorm ----------
__global__ __launch_bounds__(256)
void lnorm(float* __restrict__ x, const float* __restrict__ gamma, const float* __restrict__ beta)
{
    const int row = blockIdx.x;
    const int tid = threadIdx.x;
    float* xr = x + (size_t)row * DDIM;

    float4 v0 = *(const float4*)(xr + tid * 4);
    float4 v1 = *(const float4*)(xr + 1024 + tid * 4);
    float s  = v0.x + v0.y + v0.z + v0.w + v1.x + v1.y + v1.z + v1.w;
    float s2 = v0.x*v0.x + v0.y*v0.y + v0.z*v0.z + v0.w*v0.w
             + v1.x*v1.x + v1.y*v1.y + v1.z*v1.z + v1.w*v1.w;

    #pragma unroll
    for (int m = 1; m < 64; m <<= 1) {
        s  += __shfl_xor(s, m);
        s2 += __shfl_xor(s2, m);
    }
    __shared__ float ws1[4], ws2[4];
    if ((tid & 63) == 0) { ws1[tid >> 6] = s; ws2[tid >> 6] = s2; }
    __syncthreads();
    s  = ws1[0] + ws1[1] + ws1[2] + ws1[3];
    s2 = ws2[0] + ws2[1] + ws2[2] + ws2[3];

    const float mu  = s * (1.0f / DDIM);
    const float var = s2 * (1.0f / DDIM) - mu * mu;
    const float rstd = rsqrtf(var + 1e-5f);

    float4 g0 = *(const float4*)(gamma + tid * 4);
    float4 g1 = *(const float4*)(gamma + 1024 + tid * 4);
    float4 b0 = *(const float4*)(beta + tid * 4);
    float4 b1 = *(const float4*)(beta + 1024 + tid * 4);

    v0.x = (v0.x - mu) * rstd * g0.x + b0.x;
    v0.y = (v0.y - mu) * rstd * g0.y + b0.y;
    v0.z = (v0.z - mu) * rstd * g0.z + b0.z;
    v0.w = (v0.w - mu) * rstd * g0.w + b0.w;
    v1.x = (v1.x - mu) * rstd * g1.x + b1.x;
    v1.y = (v1.y - mu) * rstd * g1.y + b1.y;
    v1.z = (v1.z - mu) * rstd * g1.z + b1.z;
    v1.w = (v1.w - mu) * rstd * g1.w + b1.w;

    *(float4*)(xr + tid * 4) = v0;
    *(float4*)(xr + 1024 + tid * 4) = v1;
}

// ---------- launch ----------
extern "C" void kernel_launch(void* const* d_in, const int* in_sizes, int n_in,
                              void* d_out, int out_size, void* d_ws, size_t ws_size,
                              hipStream_t stream)
{
    const float* q     = (const float*)d_in[0];
    const float* k     = (const float*)d_in[1];
    const float* v     = (const float*)d_in[2];
    const float* Wq    = (const float*)d_in[3];
    const float* bq    = (const float*)d_in[4];
    const float* Wk    = (const float*)d_in[5];
    const float* bk    = (const float*)d_in[6];
    const float* Wv    = (const float*)d_in[7];
    const float* bv    = (const float*)d_in[8];
    const float* Wo    = (const float*)d_in[9];
    const float* bo    = (const float*)d_in[10];
    const float* gamma = (const float*)d_in[11];
    const float* beta  = (const float*)d_in[12];

    const size_t BD = (size_t)BDIM * DDIM;
    const size_t WSZ = (((size_t)DDIM * DDIM * 2) + 255) & ~(size_t)255;
    const size_t BSZ = ((BD * 2) + 255) & ~(size_t)255;
    char* ws = (char*)d_ws;
    size_t off = 0;
    auto alloc = [&](size_t bytes) { void* p = ws + off; off += (bytes + 255) & ~(size_t)255; return p; };

    short* Wqt = (short*)alloc(WSZ);
    short* Wkt = (short*)alloc(WSZ);
    short* Wvt = (short*)alloc(WSZ);
    short* Wot = (short*)alloc(WSZ);

    float* xout = (float*)d_out;
    const int grid = (BDIM / 256) * (DDIM / 256);   // 1024
    const int n8 = (int)(BD / 8);

    wtrans<<<dim3(DDIM / 32, DDIM / 32, 4), dim3(32, 8), 0, stream>>>(Wq, Wk, Wv, Wo, Wqt, Wkt, Wvt, Wot);

    const size_t need_large = 4 * WSZ + 6 * BSZ;    // ~839 MB

    if (ws_size >= need_large) {
        // ---- large-ws path: merged cvt + merged projection GEMMs ----
        short* qb  = (short*)alloc(BSZ);
        short* kb  = (short*)alloc(BSZ);
        short* vb  = (short*)alloc(BSZ);
        short* qpb = (short*)alloc(BSZ);
        short* kpb = (short*)alloc(BSZ);
        short* vpb = (short*)alloc(BSZ);
        short* ot  = qb;                            // qb dead after projections

        cvt3<<<dim3(4096, 1, 3), 256, 0, stream>>>(q, k, v, qb, kb, vb, n8);
        gemm8<0><<<dim3(grid, 1, 3), 512, 0, stream>>>(
            qb, kb, vb, Wqt, Wkt, Wvt, bq, bk, bv, qpb, kpb, vpb, nullptr, nullptr);
        attn<<<BDIM, 256, 0, stream>>>(qpb, kpb, vpb, ot);
        gemm8<1><<<dim3(grid, 1, 1), 512, 0, stream>>>(
            ot, ot, ot, Wot, Wot, Wot, bo, bo, bo, nullptr, nullptr, nullptr, qpb, xout);
        lnorm<<<BDIM, 256, 0, stream>>>(xout, gamma, beta);
    } else {
        // ---- sequential r6 path (544 MB, known-good) ----
        short* xb  = (short*)alloc(BSZ);            // conv buffer, then attn out
        short* qpb = (short*)alloc(BSZ);
        short* kpb = (short*)alloc(BSZ);
        short* vpb = (short*)alloc(BSZ);

        cvt1<<<4096, 256, 0, stream>>>(q, xb, n8);
        gemm8<0><<<dim3(grid, 1, 1), 512, 0, stream>>>(
            xb, xb, xb, Wqt, Wqt, Wqt, bq, bq, bq, qpb, qpb, qpb, nullptr, nullptr);
        cvt1<<<4096, 256, 0, stream>>>(k, xb, n8);
        gemm8<0><<<dim3(grid, 1, 1), 512, 0, stream>>>(
            xb, xb, xb, Wkt, Wkt, Wkt, bk, bk, bk, kpb, kpb, kpb, nullptr, nullptr);
        cvt1<<<4096, 256, 0, stream>>>(v, xb, n8);
        gemm8<0><<<dim3(grid, 1, 1), 512, 0, stream>>>(
            xb, xb, xb, Wvt, Wvt, Wvt, bv, bv, bv, vpb, vpb, vpb, nullptr, nullptr);

        attn<<<BDIM, 256, 0, stream>>>(qpb, kpb, vpb, xb);

        gemm8<1><<<dim3(grid, 1, 1), 512, 0, stream>>>(
            xb, xb, xb, Wot, Wot, Wot, bo, bo, bo, nullptr, nullptr, nullptr, qpb, xout);

        lnorm<<<BDIM, 256, 0, stream>>>(xout, gamma, beta);
    }
}